// Round 4
// baseline (2605.589 us; speedup 1.0000x reference)
//
#include <hip/hip_runtime.h>
#include <hip/hip_bf16.h>
#include <hip/hip_cooperative_groups.h>
#include <stdint.h>

namespace cg = cooperative_groups;

// Problem constants
#define NN 8192
#define MM 4096
#define DD 256
#define REGC 0.1f
#define FIC 0.8333333333333334f   // tau/(tau+reg) = 0.5/0.6
#define AMARG (1.0f/8192.0f)
#define BMARG (1.0f/4096.0f)
#define NIT 32                    // fi^2=0.694-contraction: 0.694^32 ~ 8e-6
#define QSCALE 63.75f             // u8 code: q = round(C * 63.75), C in [0,4]
#define QINV   0.01568627f        // 1/63.75
#define NBLK 256
#define NTHR 512
#define ROWS 32                   // K rows per coop block
#define SMEM_BYTES 149632         // 32*4096 + 4096*4 + 32*4 + 512*4

typedef __bf16 bf16x8_t __attribute__((ext_vector_type(8)));
typedef float f32x4_t __attribute__((ext_vector_type(4)));
typedef unsigned short us8_t __attribute__((ext_vector_type(8)));

__device__ __forceinline__ unsigned short f2bf(float f) {
    unsigned int u = __float_as_uint(f);
    u = u + 0x7FFFu + ((u >> 16) & 1u);   // RNE
    return (unsigned short)(u >> 16);
}
__device__ __forceinline__ float wsum(float v) {
    #pragma unroll
    for (int m = 32; m >= 1; m >>= 1) v += __shfl_xor(v, m, 64);
    return v;
}
__device__ __forceinline__ float wmaxr(float v) {
    #pragma unroll
    for (int m = 32; m >= 1; m >>= 1) v = fmaxf(v, __shfl_xor(v, m, 64));
    return v;
}
// row-pass: sum of K(decoded from 4 codes) * v[0..3]
__device__ __forceinline__ float dot4q(unsigned int kk, f32x4_t v, float negdec) {
    float s;
    s  = __expf((float)( kk        & 255u) * negdec) * v[0];
    s += __expf((float)((kk >> 8)  & 255u) * negdec) * v[1];
    s += __expf((float)((kk >> 16) & 255u) * negdec) * v[2];
    s += __expf((float)( kk >> 24        ) * negdec) * v[3];
    return s;
}
// col-pass: t[c] += K * uu for 4 codes
__device__ __forceinline__ void colacc4(unsigned int kk, float uu, float negdec, float* t) {
    t[0] += __expf((float)( kk        & 255u) * negdec) * uu;
    t[1] += __expf((float)((kk >> 8)  & 255u) * negdec) * uu;
    t[2] += __expf((float)((kk >> 16) & 255u) * negdec) * uu;
    t[3] += __expf((float)( kk >> 24        ) * negdec) * uu;
}
// dist: sum of x*K*vc (x = raw code)
__device__ __forceinline__ float dist4(unsigned int kk, f32x4_t vc, float negdec) {
    float x0 = (float)( kk        & 255u);
    float x1 = (float)((kk >> 8)  & 255u);
    float x2 = (float)((kk >> 16) & 255u);
    float x3 = (float)( kk >> 24        );
    float s;
    s  = x0 * __expf(x0 * negdec) * vc[0];
    s += x1 * __expf(x1 * negdec) * vc[1];
    s += x2 * __expf(x2 * negdec) * vc[2];
    s += x3 * __expf(x3 * negdec) * vc[3];
    return s;
}

// ---------------- init: zero cmax + dist slot ----------------
__global__ void init_kernel(unsigned int* __restrict__ cmaxu, float* __restrict__ out) {
    if (threadIdx.x == 0) { *cmaxu = 0u; out[(size_t)NN*DD] = 0.0f; }
}

// ---------------- normalize rows; emit srcn(f32) + srcb/tgtb(bf16) + tgtT(bf16) ----------------
__global__ void norm_kernel(const float* __restrict__ src, const float* __restrict__ tgt,
                            float* __restrict__ srcn,
                            unsigned short* __restrict__ srcb, unsigned short* __restrict__ tgtb,
                            unsigned short* __restrict__ tgtT) {
    int b = blockIdx.x, l = threadIdx.x;      // 64 threads = 1 wave per row
    bool is_src = b < NN;
    int r = is_src ? b : b - NN;
    const float* in = is_src ? src : tgt;
    unsigned short* outb = is_src ? srcb : tgtb;

    f32x4_t x = *(const f32x4_t*)(in + (size_t)r*DD + l*4);
    float s = x[0]+x[1]+x[2]+x[3];
    s = wsum(s);
    float mean = s * (1.0f/(float)DD);
    float c0=x[0]-mean, c1=x[1]-mean, c2=x[2]-mean, c3=x[3]-mean;
    float ss = c0*c0+c1*c1+c2*c2+c3*c3;
    ss = wsum(ss);
    float scale = 1.0f / fmaxf(sqrtf(ss), 1e-8f);
    f32x4_t o; o[0]=c0*scale; o[1]=c1*scale; o[2]=c2*scale; o[3]=c3*scale;
    unsigned short b0=f2bf(o[0]), b1=f2bf(o[1]), b2=f2bf(o[2]), b3=f2bf(o[3]);
    unsigned long long pk = (unsigned long long)b0 | ((unsigned long long)b1<<16)
                          | ((unsigned long long)b2<<32) | ((unsigned long long)b3<<48);
    *(unsigned long long*)(outb + (size_t)r*DD + l*4) = pk;
    if (is_src) {
        *(f32x4_t*)(srcn + (size_t)r*DD + l*4) = o;
    } else {
        tgtT[(size_t)(l*4+0)*MM + r] = b0;
        tgtT[(size_t)(l*4+1)*MM + r] = b1;
        tgtT[(size_t)(l*4+2)*MM + r] = b2;
        tgtT[(size_t)(l*4+3)*MM + r] = b3;
    }
}

// ---------------- dots = srcn @ tgtn^T (MFMA bf16) -> u8 cost codes + global max cost ----------------
__launch_bounds__(256)
__global__ void dot_kernel(const unsigned short* __restrict__ srcb,
                           const unsigned short* __restrict__ tgtb,
                           unsigned char* __restrict__ Kq,
                           unsigned int* __restrict__ cmaxu) {
    __shared__ unsigned short Al[64][40];
    __shared__ unsigned short Bl[64][40];
    __shared__ float redsh[4];
    int tid = threadIdx.x;
    int bi = blockIdx.x & 127, bj = blockIdx.x >> 7;
    int i0 = bi * 64, j0 = bj * 64;
    int l = tid & 63, wid = tid >> 6;
    int wm = wid >> 1, wn = wid & 1;
    int fr = l & 15, kc = (l >> 4) * 8;
    f32x4_t acc[2][2] = {};
    int sr = tid >> 2, sc = (tid & 3) * 8;
    for (int kk = 0; kk < DD; kk += 32) {
        __syncthreads();
        *(uint4*)(&Al[sr][sc]) = *(const uint4*)(srcb + (size_t)(i0+sr)*DD + kk + sc);
        *(uint4*)(&Bl[sr][sc]) = *(const uint4*)(tgtb + (size_t)(j0+sr)*DD + kk + sc);
        __syncthreads();
        bf16x8_t a0 = *(const bf16x8_t*)(&Al[wm*32 + fr][kc]);
        bf16x8_t a1 = *(const bf16x8_t*)(&Al[wm*32 + 16 + fr][kc]);
        bf16x8_t b0 = *(const bf16x8_t*)(&Bl[wn*32 + fr][kc]);
        bf16x8_t b1 = *(const bf16x8_t*)(&Bl[wn*32 + 16 + fr][kc]);
        acc[0][0] = __builtin_amdgcn_mfma_f32_16x16x32_bf16(a0, b0, acc[0][0], 0, 0, 0);
        acc[0][1] = __builtin_amdgcn_mfma_f32_16x16x32_bf16(a0, b1, acc[0][1], 0, 0, 0);
        acc[1][0] = __builtin_amdgcn_mfma_f32_16x16x32_bf16(a1, b0, acc[1][0], 0, 0, 0);
        acc[1][1] = __builtin_amdgcn_mfma_f32_16x16x32_bf16(a1, b1, acc[1][1], 0, 0, 0);
    }
    int rq = (l >> 4) * 4;
    float mx = 0.0f;
    #pragma unroll
    for (int fm = 0; fm < 2; ++fm) {
        #pragma unroll
        for (int fn = 0; fn < 2; ++fn) {
            #pragma unroll
            for (int q = 0; q < 4; ++q) {
                int row = i0 + wm*32 + fm*16 + rq + q;
                int col = j0 + wn*32 + fn*16 + fr;
                float C = fmaxf(2.0f - 2.0f*acc[fm][fn][q], 0.0f);
                mx = fmaxf(mx, C);
                Kq[(size_t)row*MM + col] =
                    (unsigned char)(fminf(C*QSCALE, 255.0f) + 0.5f);
            }
        }
    }
    mx = wmaxr(mx);
    if (l == 0) redsh[wid] = mx;
    __syncthreads();
    if (tid == 0) {
        float m = fmaxf(fmaxf(redsh[0], redsh[1]), fmaxf(redsh[2], redsh[3]));
        atomicMax(cmaxu, __float_as_uint(m));
    }
}

// ---------------- the whole Sinkhorn loop: cooperative, K slab LDS-resident ----------------
// 256 blocks x 512 thr, 1 block/CU (146 KB LDS). Block owns 32 rows of Kq.
// Per iter: A: row sums -> u (block-local); B: col partials -> part[bid][:];
// gridsync; C (blocks<64): reduce partials -> v_g; gridsync; reload v_lds.
// Tail: dist = sum C*u*K*v from the LDS slab.
__launch_bounds__(NTHR)
__global__ void sink_coop(const unsigned char* __restrict__ Kq,
                          float* __restrict__ part,
                          float* __restrict__ u_out,
                          float* __restrict__ v_g,
                          const unsigned int* __restrict__ cmaxu,
                          float* __restrict__ out) {
    extern __shared__ unsigned char smem[];
    unsigned char* Kl = smem;                          // [32][4096] u8
    float* v_lds = (float*)(smem + ROWS*MM);           // [4096]
    float* u_lds = v_lds + MM;                         // [32]
    float* red   = u_lds + 32;                         // [8][64]

    cg::grid_group grid = cg::this_grid();
    int tid = threadIdx.x, l = tid & 63, w = tid >> 6;
    int bid = blockIdx.x;
    float cmax = __uint_as_float(*cmaxu);
    float negdec = -0.15686275f / cmax;   // -1/(63.75*REG*cmax)

    // stage 128 KB slab global -> LDS
    {
        const unsigned char* srcp = Kq + (size_t)bid * (ROWS*MM);
        #pragma unroll
        for (int q = 0; q < 16; ++q) {
            int off = (q*NTHR + tid) * 16;
            *(uint4*)(Kl + off) = *(const uint4*)(srcp + off);
        }
    }
    #pragma unroll
    for (int q = 0; q < 8; ++q) v_lds[tid*8 + q] = 1.0f;
    __syncthreads();

    int jb = w*512 + l*8;   // col slice for phases B / dist

    for (int it = 0; it < NIT; ++it) {
        // ---- Phase A: rows 4w..4w+3, full 4096 cols
        float racc[4] = {0.f, 0.f, 0.f, 0.f};
        int rbase = 4*w;
        #pragma unroll
        for (int c = 0; c < 4; ++c) {
            int cb = c*1024 + l*16;
            f32x4_t v0 = *(const f32x4_t*)(v_lds + cb);
            f32x4_t v1 = *(const f32x4_t*)(v_lds + cb + 4);
            f32x4_t v2 = *(const f32x4_t*)(v_lds + cb + 8);
            f32x4_t v3 = *(const f32x4_t*)(v_lds + cb + 12);
            #pragma unroll
            for (int r = 0; r < 4; ++r) {
                uint4 kk = *(const uint4*)(Kl + (size_t)(rbase + r)*MM + cb);
                float s = dot4q(kk.x, v0, negdec);
                s += dot4q(kk.y, v1, negdec);
                s += dot4q(kk.z, v2, negdec);
                s += dot4q(kk.w, v3, negdec);
                racc[r] += s;
            }
        }
        #pragma unroll
        for (int r = 0; r < 4; ++r) {
            racc[r] = wsum(racc[r]);
            float uu = __expf(FIC * __logf(AMARG / racc[r]));
            if (l == 0) {
                u_lds[rbase + r] = uu;
                if (it == NIT-1) u_out[bid*ROWS + rbase + r] = uu;
            }
        }
        __syncthreads();
        // ---- Phase B: col partials for cols jb..jb+8 over 32 rows
        float tacc[8] = {0.f,0.f,0.f,0.f,0.f,0.f,0.f,0.f};
        #pragma unroll 4
        for (int r = 0; r < ROWS; ++r) {
            uint2 kk = *(const uint2*)(Kl + (size_t)r*MM + jb);
            float uu = u_lds[r];
            colacc4(kk.x, uu, negdec, &tacc[0]);
            colacc4(kk.y, uu, negdec, &tacc[4]);
        }
        {
            float* pp = part + (size_t)bid*MM + jb;
            f32x4_t o0; o0[0]=tacc[0]; o0[1]=tacc[1]; o0[2]=tacc[2]; o0[3]=tacc[3];
            f32x4_t o1; o1[0]=tacc[4]; o1[1]=tacc[5]; o1[2]=tacc[6]; o1[3]=tacc[7];
            *(f32x4_t*)pp = o0;
            *(f32x4_t*)(pp + 4) = o1;
        }
        grid.sync();
        // ---- Phase C: blocks 0..63 reduce 256 partials -> v
        if (bid < 64) {
            int j = bid*64 + l;
            float s = 0.0f;
            #pragma unroll 8
            for (int p = w*32; p < w*32 + 32; ++p) s += part[(size_t)p*MM + j];
            red[w*64 + l] = s;
            __syncthreads();
            if (w == 0) {
                float t = red[l];
                #pragma unroll
                for (int ww = 1; ww < 8; ++ww) t += red[ww*64 + l];
                v_g[j] = __expf(FIC * __logf(BMARG / t));
            }
        }
        grid.sync();
        // reload v
        {
            f32x4_t a0 = *(const f32x4_t*)(v_g + tid*8);
            f32x4_t a1 = *(const f32x4_t*)(v_g + tid*8 + 4);
            *(f32x4_t*)(v_lds + tid*8) = a0;
            *(f32x4_t*)(v_lds + tid*8 + 4) = a1;
        }
        __syncthreads();
    }

    // ---- dist tail: sum_ij C*u*K*v over the LDS slab (C = q*QINV folded at the end)
    f32x4_t vc0 = *(const f32x4_t*)(v_lds + jb);
    f32x4_t vc1 = *(const f32x4_t*)(v_lds + jb + 4);
    float dacc = 0.0f;
    #pragma unroll 4
    for (int r = 0; r < ROWS; ++r) {
        uint2 kk = *(const uint2*)(Kl + (size_t)r*MM + jb);
        float uu = u_lds[r];
        dacc += (dist4(kk.x, vc0, negdec) + dist4(kk.y, vc1, negdec)) * uu;
    }
    dacc = wsum(dacc);
    if (l == 0) red[w] = dacc;
    __syncthreads();
    if (tid == 0) {
        float t = 0.0f;
        #pragma unroll
        for (int ww = 0; ww < 8; ++ww) t += red[ww];
        atomicAdd(out + (size_t)NN*DD, t * QINV);
    }
}

// ---------------- WT[d][j] = v_j * tgtT[d][j] (bf16) ----------------
__global__ void wt_kernel(const unsigned short* __restrict__ tgtT,
                          const float* __restrict__ v,
                          unsigned short* __restrict__ WT) {
    int idx = blockIdx.x * 256 + threadIdx.x;   // 512 blocks x 256 thr
    int d = idx >> 9, jc = (idx & 511) * 8;
    us8_t tv = *(const us8_t*)(tgtT + (size_t)d*MM + jc);
    f32x4_t v0 = *(const f32x4_t*)(v + jc);
    f32x4_t v1 = *(const f32x4_t*)(v + jc + 4);
    us8_t o;
    #pragma unroll
    for (int q = 0; q < 8; ++q) {
        float vv = (q < 4) ? v0[q] : v1[q-4];
        float kf = __uint_as_float(((unsigned int)tv[q]) << 16);
        o[q] = f2bf(kf * vv);
    }
    *(us8_t*)(WT + (size_t)d*MM + jc) = o;
}

// ---------------- finalize: out = srcn + diag(u)*(K @ WT^T), K decoded from codes ----------------
// 256 blocks x 512 thr; block = 32 rows; wave = 2 d-frags x 2 row-halves = 4 MFMA / 3 loads.
__launch_bounds__(NTHR)
__global__ void final_kernel(const unsigned char* __restrict__ Kq,
                             const float* __restrict__ u,
                             const unsigned short* __restrict__ WT,
                             const float* __restrict__ srcn,
                             const unsigned int* __restrict__ cmaxu,
                             float* __restrict__ out) {
    int tid = threadIdx.x, l = tid & 63, w = tid >> 6;
    int i0 = blockIdx.x * 32;
    int fr = l & 15, kq8 = (l >> 4) * 8;
    float negdec = -0.15686275f / __uint_as_float(*cmaxu);
    f32x4_t acc[2][2] = {};
    for (int jc = 0; jc < MM; jc += 32) {
        int off = jc + kq8;
        bf16x8_t afr[2];
        #pragma unroll
        for (int h = 0; h < 2; ++h) {
            uint2 kk = *(const uint2*)(Kq + (size_t)(i0 + h*16 + fr)*MM + off);
            float f0 = __expf((float)( kk.x        & 255u)*negdec);
            float f1 = __expf((float)((kk.x >> 8)  & 255u)*negdec);
            float f2 = __expf((float)((kk.x >> 16) & 255u)*negdec);
            float f3 = __expf((float)( kk.x >> 24        )*negdec);
            float f4 = __expf((float)( kk.y        & 255u)*negdec);
            float f5 = __expf((float)((kk.y >> 8)  & 255u)*negdec);
            float f6 = __expf((float)((kk.y >> 16) & 255u)*negdec);
            float f7 = __expf((float)( kk.y >> 24        )*negdec);
            uint4 pk;
            asm("v_cvt_pk_bf16_f32 %0, %1, %2" : "=v"(pk.x) : "v"(f0), "v"(f1));
            asm("v_cvt_pk_bf16_f32 %0, %1, %2" : "=v"(pk.y) : "v"(f2), "v"(f3));
            asm("v_cvt_pk_bf16_f32 %0, %1, %2" : "=v"(pk.z) : "v"(f4), "v"(f5));
            asm("v_cvt_pk_bf16_f32 %0, %1, %2" : "=v"(pk.w) : "v"(f6), "v"(f7));
            afr[h] = __builtin_bit_cast(bf16x8_t, pk);
        }
        #pragma unroll
        for (int b = 0; b < 2; ++b) {
            int drow = (2*w + b)*16 + fr;
            bf16x8_t bfr = *(const bf16x8_t*)(WT + (size_t)drow*MM + off);
            acc[0][b] = __builtin_amdgcn_mfma_f32_16x16x32_bf16(afr[0], bfr, acc[0][b], 0, 0, 0);
            acc[1][b] = __builtin_amdgcn_mfma_f32_16x16x32_bf16(afr[1], bfr, acc[1][b], 0, 0, 0);
        }
    }
    int rq = (l >> 4) * 4;
    #pragma unroll
    for (int h = 0; h < 2; ++h) {
        #pragma unroll
        for (int qq = 0; qq < 4; ++qq) {
            int i = i0 + h*16 + rq + qq;
            float uu = u[i];
            #pragma unroll
            for (int b = 0; b < 2; ++b) {
                int d = (2*w + b)*16 + fr;
                size_t idx = (size_t)i*DD + d;
                out[idx] = srcn[idx] + uu*acc[h][b][qq];
            }
        }
    }
}

// ---------------- host ----------------
extern "C" void kernel_launch(void* const* d_in, const int* in_sizes, int n_in,
                              void* d_out, int out_size, void* d_ws, size_t ws_size,
                              hipStream_t stream) {
    const float* src = (const float*)d_in[0];
    const float* tgt = (const float*)d_in[1];
    float* out = (float*)d_out;
    char* ws = (char*)d_ws;

    constexpr size_t OFF_SRCN = 0;                        // 8192*256*4  = 8388608
    constexpr size_t OFF_SRCB = 8388608;                  // 8192*256*2  = 4194304
    constexpr size_t OFF_TGTB = 12582912;                 // 4096*256*2  = 2097152
    constexpr size_t OFF_TGTT = 14680064;                 // 256*4096*2  = 2097152
    constexpr size_t OFF_WT   = 16777216;                 // 256*4096*2  = 2097152
    constexpr size_t OFF_KQ   = 18874368;                 // 8192*4096*1 = 33554432
    constexpr size_t OFF_PART = 52428800;                 // 256*4096*4  = 4194304
    constexpr size_t OFF_U    = 56623104;                 // 8192*4
    constexpr size_t OFF_V    = 56655872;                 // 4096*4
    constexpr size_t OFF_CMAX = 56672256;                 // 4

    float* srcn = (float*)(ws + OFF_SRCN);
    unsigned short* srcb = (unsigned short*)(ws + OFF_SRCB);
    unsigned short* tgtb = (unsigned short*)(ws + OFF_TGTB);
    unsigned short* tgtT = (unsigned short*)(ws + OFF_TGTT);
    unsigned short* WT   = (unsigned short*)(ws + OFF_WT);
    unsigned char* Kq    = (unsigned char*)(ws + OFF_KQ);
    float* part = (float*)(ws + OFF_PART);
    float* u    = (float*)(ws + OFF_U);
    float* v    = (float*)(ws + OFF_V);
    unsigned int* cmaxu = (unsigned int*)(ws + OFF_CMAX);

    init_kernel<<<1, 64, 0, stream>>>(cmaxu, out);
    norm_kernel<<<NN + MM, 64, 0, stream>>>(src, tgt, srcn, srcb, tgtb, tgtT);
    dot_kernel<<<(NN/64)*(MM/64), 256, 0, stream>>>(srcb, tgtb, Kq, cmaxu);

    {
        static int attr_done = 0;
        if (!attr_done) {
            (void)hipFuncSetAttribute((const void*)sink_coop,
                                      hipFuncAttributeMaxDynamicSharedMemorySize,
                                      SMEM_BYTES);
            attr_done = 1;
        }
        const unsigned char* Kq_c = Kq;
        const unsigned int* cmax_c = cmaxu;
        void* cargs[] = { (void*)&Kq_c, (void*)&part, (void*)&u, (void*)&v,
                          (void*)&cmax_c, (void*)&out };
        hipLaunchCooperativeKernel((const void*)sink_coop, dim3(NBLK), dim3(NTHR),
                                   cargs, SMEM_BYTES, stream);
    }

    wt_kernel<<<512, 256, 0, stream>>>(tgtT, v, WT);
    final_kernel<<<NN/32, NTHR, 0, stream>>>(Kq, u, WT, srcn, cmaxu, out);
}

// Round 5
// 803.742 us; speedup vs baseline: 3.2418x; 3.2418x over previous
//
#include <hip/hip_runtime.h>
#include <hip/hip_bf16.h>
#include <stdint.h>

// Problem constants
#define NN 8192
#define MM 4096
#define DD 256
#define REGC 0.1f
#define FIC 0.8333333333333334f   // tau/(tau+reg) = 0.5/0.6
#define AMARG (1.0f/8192.0f)
#define BMARG (1.0f/4096.0f)
#define NIT 24                    // 0.694^24 * 8.3 ~ 1.3e-3 << 2% K-quantization error
#define QSCALE 63.75f             // u8 code: q = round(C * 63.75), C in [0,4]
#define QINV   0.01568627f        // 1/63.75

typedef __bf16 bf16x8_t __attribute__((ext_vector_type(8)));
typedef float f32x4_t __attribute__((ext_vector_type(4)));
typedef unsigned short us8_t __attribute__((ext_vector_type(8)));

__device__ __forceinline__ unsigned short f2bf(float f) {
    unsigned int u = __float_as_uint(f);
    u = u + 0x7FFFu + ((u >> 16) & 1u);   // RNE
    return (unsigned short)(u >> 16);
}
__device__ __forceinline__ float wsum(float v) {
    #pragma unroll
    for (int m = 32; m >= 1; m >>= 1) v += __shfl_xor(v, m, 64);
    return v;
}
__device__ __forceinline__ float wmaxr(float v) {
    #pragma unroll
    for (int m = 32; m >= 1; m >>= 1) v = fmaxf(v, __shfl_xor(v, m, 64));
    return v;
}
// col-pass: t[0..3] += K * uu for 4 codes
__device__ __forceinline__ void colacc4(unsigned int kk, float uu, float negdec, float* t) {
    t[0] += __expf((float)( kk        & 255u) * negdec) * uu;
    t[1] += __expf((float)((kk >> 8)  & 255u) * negdec) * uu;
    t[2] += __expf((float)((kk >> 16) & 255u) * negdec) * uu;
    t[3] += __expf((float)( kk >> 24        ) * negdec) * uu;
}

// ---------------- init: zero cmax + dist slot ----------------
__global__ void init_kernel(unsigned int* __restrict__ cmaxu, float* __restrict__ out) {
    if (threadIdx.x == 0) { *cmaxu = 0u; out[(size_t)NN*DD] = 0.0f; }
}

// ---------------- normalize rows; emit srcn(f32) + srcb/tgtb(bf16) + tgtT(bf16) ----------------
__global__ void norm_kernel(const float* __restrict__ src, const float* __restrict__ tgt,
                            float* __restrict__ srcn,
                            unsigned short* __restrict__ srcb, unsigned short* __restrict__ tgtb,
                            unsigned short* __restrict__ tgtT) {
    int b = blockIdx.x, l = threadIdx.x;      // 64 threads = 1 wave per row
    bool is_src = b < NN;
    int r = is_src ? b : b - NN;
    const float* in = is_src ? src : tgt;
    unsigned short* outb = is_src ? srcb : tgtb;

    f32x4_t x = *(const f32x4_t*)(in + (size_t)r*DD + l*4);
    float s = x[0]+x[1]+x[2]+x[3];
    s = wsum(s);
    float mean = s * (1.0f/(float)DD);
    float c0=x[0]-mean, c1=x[1]-mean, c2=x[2]-mean, c3=x[3]-mean;
    float ss = c0*c0+c1*c1+c2*c2+c3*c3;
    ss = wsum(ss);
    float scale = 1.0f / fmaxf(sqrtf(ss), 1e-8f);
    f32x4_t o; o[0]=c0*scale; o[1]=c1*scale; o[2]=c2*scale; o[3]=c3*scale;
    unsigned short b0=f2bf(o[0]), b1=f2bf(o[1]), b2=f2bf(o[2]), b3=f2bf(o[3]);
    unsigned long long pk = (unsigned long long)b0 | ((unsigned long long)b1<<16)
                          | ((unsigned long long)b2<<32) | ((unsigned long long)b3<<48);
    *(unsigned long long*)(outb + (size_t)r*DD + l*4) = pk;
    if (is_src) {
        *(f32x4_t*)(srcn + (size_t)r*DD + l*4) = o;
    } else {
        tgtT[(size_t)(l*4+0)*MM + r] = b0;
        tgtT[(size_t)(l*4+1)*MM + r] = b1;
        tgtT[(size_t)(l*4+2)*MM + r] = b2;
        tgtT[(size_t)(l*4+3)*MM + r] = b3;
    }
}

// ---------------- dots = srcn @ tgtn^T (MFMA bf16) -> u8 cost codes + global max cost ----------------
__launch_bounds__(256)
__global__ void dot_kernel(const unsigned short* __restrict__ srcb,
                           const unsigned short* __restrict__ tgtb,
                           unsigned char* __restrict__ Kq,
                           unsigned int* __restrict__ cmaxu) {
    __shared__ unsigned short Al[64][40];
    __shared__ unsigned short Bl[64][40];
    __shared__ float redsh[4];
    int tid = threadIdx.x;
    int bi = blockIdx.x & 127, bj = blockIdx.x >> 7;
    int i0 = bi * 64, j0 = bj * 64;
    int l = tid & 63, wid = tid >> 6;
    int wm = wid >> 1, wn = wid & 1;
    int fr = l & 15, kc = (l >> 4) * 8;
    f32x4_t acc[2][2] = {};
    int sr = tid >> 2, sc = (tid & 3) * 8;
    for (int kk = 0; kk < DD; kk += 32) {
        __syncthreads();
        *(uint4*)(&Al[sr][sc]) = *(const uint4*)(srcb + (size_t)(i0+sr)*DD + kk + sc);
        *(uint4*)(&Bl[sr][sc]) = *(const uint4*)(tgtb + (size_t)(j0+sr)*DD + kk + sc);
        __syncthreads();
        bf16x8_t a0 = *(const bf16x8_t*)(&Al[wm*32 + fr][kc]);
        bf16x8_t a1 = *(const bf16x8_t*)(&Al[wm*32 + 16 + fr][kc]);
        bf16x8_t b0 = *(const bf16x8_t*)(&Bl[wn*32 + fr][kc]);
        bf16x8_t b1 = *(const bf16x8_t*)(&Bl[wn*32 + 16 + fr][kc]);
        acc[0][0] = __builtin_amdgcn_mfma_f32_16x16x32_bf16(a0, b0, acc[0][0], 0, 0, 0);
        acc[0][1] = __builtin_amdgcn_mfma_f32_16x16x32_bf16(a0, b1, acc[0][1], 0, 0, 0);
        acc[1][0] = __builtin_amdgcn_mfma_f32_16x16x32_bf16(a1, b0, acc[1][0], 0, 0, 0);
        acc[1][1] = __builtin_amdgcn_mfma_f32_16x16x32_bf16(a1, b1, acc[1][1], 0, 0, 0);
    }
    int rq = (l >> 4) * 4;
    float mx = 0.0f;
    #pragma unroll
    for (int fm = 0; fm < 2; ++fm) {
        #pragma unroll
        for (int fn = 0; fn < 2; ++fn) {
            #pragma unroll
            for (int q = 0; q < 4; ++q) {
                int row = i0 + wm*32 + fm*16 + rq + q;
                int col = j0 + wn*32 + fn*16 + fr;
                float C = fmaxf(2.0f - 2.0f*acc[fm][fn][q], 0.0f);
                mx = fmaxf(mx, C);
                Kq[(size_t)row*MM + col] =
                    (unsigned char)(fminf(C*QSCALE, 255.0f) + 0.5f);
            }
        }
    }
    mx = wmaxr(mx);
    if (l == 0) redsh[wid] = mx;
    __syncthreads();
    if (tid == 0) {
        float m = fmaxf(fmaxf(redsh[0], redsh[1]), fmaxf(redsh[2], redsh[3]));
        atomicMax(cmaxu, __float_as_uint(m));
    }
}

// ---------------- u-pass: u_i = (a / sum_j K_ij v_j)^fi, K decoded from u8 codes ----------------
// 256 blocks x 512 thr; block = 32 rows; wave = 4 rows; lane l owns cols {l*4 + 256u}.
// v in LDS; lane's v chunks (chunk idx l + 64u) are the canonical conflict-free b128 pattern.
__launch_bounds__(512)
__global__ void upass_kernel(const unsigned char* __restrict__ Kq,
                             const float* __restrict__ vin,
                             float* __restrict__ uout,
                             const unsigned int* __restrict__ cmaxu,
                             int first) {
    __shared__ float v_lds[MM];
    int tid = threadIdx.x, l = tid & 63, w = tid >> 6;
    float negdec = -0.15686275f / __uint_as_float(*cmaxu);   // -1/(63.75*REG*cmax)
    if (first) {
        #pragma unroll
        for (int q = 0; q < 8; ++q) v_lds[tid*8 + q] = 1.0f;
    } else {
        f32x4_t a0 = *(const f32x4_t*)(vin + tid*8);
        f32x4_t a1 = *(const f32x4_t*)(vin + tid*8 + 4);
        *(f32x4_t*)(v_lds + tid*8) = a0;
        *(f32x4_t*)(v_lds + tid*8 + 4) = a1;
    }
    __syncthreads();
    f32x4_t vr[16];
    #pragma unroll
    for (int u = 0; u < 16; ++u) vr[u] = *(const f32x4_t*)(v_lds + l*4 + 256*u);
    int rbase = blockIdx.x * 32 + 4*w;
    const unsigned char* Kp = Kq + (size_t)rbase*MM + l*4;
    float r0, r1, r2, r3;
    #pragma unroll
    for (int r = 0; r < 4; ++r) {
        unsigned int code[16];
        #pragma unroll
        for (int u = 0; u < 16; ++u)
            code[u] = *(const unsigned int*)(Kp + (size_t)r*MM + 256*u);
        float s = 0.0f;
        #pragma unroll
        for (int u = 0; u < 16; ++u) {
            unsigned int k = code[u];
            s += __expf((float)( k        & 255u) * negdec) * vr[u][0];
            s += __expf((float)((k >> 8)  & 255u) * negdec) * vr[u][1];
            s += __expf((float)((k >> 16) & 255u) * negdec) * vr[u][2];
            s += __expf((float)( k >> 24        ) * negdec) * vr[u][3];
        }
        s = wsum(s);
        if (r == 0) r0 = s; else if (r == 1) r1 = s; else if (r == 2) r2 = s; else r3 = s;
    }
    float sel = (l == 1) ? r1 : (l == 2) ? r2 : (l == 3) ? r3 : r0;
    if (l < 4) uout[rbase + l] = __expf(FIC * __logf(AMARG / sel));
}

// ---------------- col-partials: part[b][j] = sum_{i in block b} K_ij u_i ----------------
// 256 blocks x 512 thr; block = 32 rows (same rows as upass block b -> same XCD L2 slice);
// wave owns a 512-col slice; lane owns 8 cols; 32 rows in 4 pipelined groups of 8.
__launch_bounds__(512)
__global__ void colpart_kernel(const unsigned char* __restrict__ Kq,
                               const float* __restrict__ u,
                               float* __restrict__ part,
                               const unsigned int* __restrict__ cmaxu) {
    __shared__ float u_lds[32];
    int tid = threadIdx.x, l = tid & 63, w = tid >> 6;
    int row0 = blockIdx.x * 32;
    float negdec = -0.15686275f / __uint_as_float(*cmaxu);
    if (tid < 32) u_lds[tid] = u[row0 + tid];
    __syncthreads();
    int jb = w*512 + l*8;
    const unsigned char* Kp = Kq + (size_t)row0*MM + jb;
    float tacc[8] = {0.f,0.f,0.f,0.f,0.f,0.f,0.f,0.f};
    #pragma unroll
    for (int g = 0; g < 4; ++g) {
        uint2 cc[8];
        #pragma unroll
        for (int r = 0; r < 8; ++r)
            cc[r] = *(const uint2*)(Kp + (size_t)(g*8 + r)*MM);
        #pragma unroll
        for (int r = 0; r < 8; ++r) {
            float uu = u_lds[g*8 + r];
            colacc4(cc[r].x, uu, negdec, &tacc[0]);
            colacc4(cc[r].y, uu, negdec, &tacc[4]);
        }
    }
    float* pp = part + (size_t)blockIdx.x*MM + jb;
    f32x4_t o0; o0[0]=tacc[0]; o0[1]=tacc[1]; o0[2]=tacc[2]; o0[3]=tacc[3];
    f32x4_t o1; o1[0]=tacc[4]; o1[1]=tacc[5]; o1[2]=tacc[6]; o1[3]=tacc[7];
    *(f32x4_t*)pp = o0;
    *(f32x4_t*)(pp + 4) = o1;
}

// ---------------- v-reduce: v_j = (b / sum_p part[p][j])^fi  (256 partials) ----------------
__launch_bounds__(512)
__global__ void vred_kernel(const float* __restrict__ part, float* __restrict__ vout) {
    __shared__ float red[8][64];
    int tid = threadIdx.x, l = tid & 63, w = tid >> 6;
    int j = blockIdx.x * 64 + l;
    float s = 0.0f;
    #pragma unroll 8
    for (int p = w*32; p < w*32 + 32; ++p) s += part[(size_t)p*MM + j];
    red[w][l] = s;
    __syncthreads();
    if (w == 0) {
        float t = red[0][l];
        #pragma unroll
        for (int ww = 1; ww < 8; ++ww) t += red[ww][l];
        vout[j] = __expf(FIC * __logf(BMARG / t));
    }
}

// ---------------- WT[d][j] = v_j * tgtT[d][j] (bf16) ----------------
__global__ void wt_kernel(const unsigned short* __restrict__ tgtT,
                          const float* __restrict__ v,
                          unsigned short* __restrict__ WT) {
    int idx = blockIdx.x * 256 + threadIdx.x;   // 512 blocks x 256 thr
    int d = idx >> 9, jc = (idx & 511) * 8;
    us8_t tv = *(const us8_t*)(tgtT + (size_t)d*MM + jc);
    f32x4_t v0 = *(const f32x4_t*)(v + jc);
    f32x4_t v1 = *(const f32x4_t*)(v + jc + 4);
    us8_t o;
    #pragma unroll
    for (int q = 0; q < 8; ++q) {
        float vv = (q < 4) ? v0[q] : v1[q-4];
        float kf = __uint_as_float(((unsigned int)tv[q]) << 16);
        o[q] = f2bf(kf * vv);
    }
    *(us8_t*)(WT + (size_t)d*MM + jc) = o;
}

// ---------------- finalize: out = srcn + diag(u)*(K @ WT^T); dist fused on wave 0 ----------------
// 256 blocks x 512 thr; block = 32 rows; wave = 2 d-frags x 2 row-halves = 4 MFMA / 3 loads.
__launch_bounds__(512)
__global__ void final_kernel(const unsigned char* __restrict__ Kq,
                             const float* __restrict__ u,
                             const float* __restrict__ v,
                             const unsigned short* __restrict__ WT,
                             const float* __restrict__ srcn,
                             const unsigned int* __restrict__ cmaxu,
                             float* __restrict__ out) {
    int tid = threadIdx.x, l = tid & 63, w = tid >> 6;
    int i0 = blockIdx.x * 32;
    int fr = l & 15, kq8 = (l >> 4) * 8;
    float negdec = -0.15686275f / __uint_as_float(*cmaxu);
    float u_h0 = u[i0 + fr], u_h1 = u[i0 + 16 + fr];   // dist (wave 0)
    f32x4_t acc[2][2] = {};
    float distp = 0.0f;
    for (int jc = 0; jc < MM; jc += 32) {
        int off = jc + kq8;
        bf16x8_t afr[2];
        #pragma unroll
        for (int h = 0; h < 2; ++h) {
            uint2 kk = *(const uint2*)(Kq + (size_t)(i0 + h*16 + fr)*MM + off);
            float q0 = (float)( kk.x        & 255u);
            float q1 = (float)((kk.x >> 8)  & 255u);
            float q2 = (float)((kk.x >> 16) & 255u);
            float q3 = (float)( kk.x >> 24        );
            float q4 = (float)( kk.y        & 255u);
            float q5 = (float)((kk.y >> 8)  & 255u);
            float q6 = (float)((kk.y >> 16) & 255u);
            float q7 = (float)( kk.y >> 24        );
            float f0 = __expf(q0*negdec), f1 = __expf(q1*negdec);
            float f2 = __expf(q2*negdec), f3 = __expf(q3*negdec);
            float f4 = __expf(q4*negdec), f5 = __expf(q5*negdec);
            float f6 = __expf(q6*negdec), f7 = __expf(q7*negdec);
            if (w == 0) {
                f32x4_t va = *(const f32x4_t*)(v + off);
                f32x4_t vb = *(const f32x4_t*)(v + off + 4);
                float uh = h ? u_h1 : u_h0;
                float d = q0*f0*va[0] + q1*f1*va[1] + q2*f2*va[2] + q3*f3*va[3]
                        + q4*f4*vb[0] + q5*f5*vb[1] + q6*f6*vb[2] + q7*f7*vb[3];
                distp += uh * d;
            }
            uint4 pk;
            asm("v_cvt_pk_bf16_f32 %0, %1, %2" : "=v"(pk.x) : "v"(f0), "v"(f1));
            asm("v_cvt_pk_bf16_f32 %0, %1, %2" : "=v"(pk.y) : "v"(f2), "v"(f3));
            asm("v_cvt_pk_bf16_f32 %0, %1, %2" : "=v"(pk.z) : "v"(f4), "v"(f5));
            asm("v_cvt_pk_bf16_f32 %0, %1, %2" : "=v"(pk.w) : "v"(f6), "v"(f7));
            afr[h] = __builtin_bit_cast(bf16x8_t, pk);
        }
        #pragma unroll
        for (int b = 0; b < 2; ++b) {
            int drow = (2*w + b)*16 + fr;
            bf16x8_t bfr = *(const bf16x8_t*)(WT + (size_t)drow*MM + off);
            acc[0][b] = __builtin_amdgcn_mfma_f32_16x16x32_bf16(afr[0], bfr, acc[0][b], 0, 0, 0);
            acc[1][b] = __builtin_amdgcn_mfma_f32_16x16x32_bf16(afr[1], bfr, acc[1][b], 0, 0, 0);
        }
    }
    int rq = (l >> 4) * 4;
    #pragma unroll
    for (int h = 0; h < 2; ++h) {
        #pragma unroll
        for (int qq = 0; qq < 4; ++qq) {
            int i = i0 + h*16 + rq + qq;
            float uu = u[i];
            #pragma unroll
            for (int b = 0; b < 2; ++b) {
                int d = (2*w + b)*16 + fr;
                size_t idx = (size_t)i*DD + d;
                out[idx] = srcn[idx] + uu*acc[h][b][qq];
            }
        }
    }
    if (w == 0) {
        distp = wsum(distp);
        if (l == 0) atomicAdd(out + (size_t)NN*DD, distp * QINV);
    }
}

// ---------------- host ----------------
extern "C" void kernel_launch(void* const* d_in, const int* in_sizes, int n_in,
                              void* d_out, int out_size, void* d_ws, size_t ws_size,
                              hipStream_t stream) {
    const float* src = (const float*)d_in[0];
    const float* tgt = (const float*)d_in[1];
    float* out = (float*)d_out;
    char* ws = (char*)d_ws;

    constexpr size_t OFF_SRCN = 0;                        // 8192*256*4  = 8388608
    constexpr size_t OFF_SRCB = 8388608;                  // 8192*256*2  = 4194304
    constexpr size_t OFF_TGTB = 12582912;                 // 4096*256*2  = 2097152
    constexpr size_t OFF_TGTT = 14680064;                 // 256*4096*2  = 2097152
    constexpr size_t OFF_WT   = 16777216;                 // 256*4096*2  = 2097152
    constexpr size_t OFF_KQ   = 18874368;                 // 8192*4096*1 = 33554432
    constexpr size_t OFF_PART = 52428800;                 // 256*4096*4  = 4194304
    constexpr size_t OFF_U    = 56623104;                 // 8192*4
    constexpr size_t OFF_V    = 56655872;                 // 4096*4
    constexpr size_t OFF_CMAX = 56672256;                 // 4

    float* srcn = (float*)(ws + OFF_SRCN);
    unsigned short* srcb = (unsigned short*)(ws + OFF_SRCB);
    unsigned short* tgtb = (unsigned short*)(ws + OFF_TGTB);
    unsigned short* tgtT = (unsigned short*)(ws + OFF_TGTT);
    unsigned short* WT   = (unsigned short*)(ws + OFF_WT);
    unsigned char* Kq    = (unsigned char*)(ws + OFF_KQ);
    float* part = (float*)(ws + OFF_PART);
    float* u    = (float*)(ws + OFF_U);
    float* v    = (float*)(ws + OFF_V);
    unsigned int* cmaxu = (unsigned int*)(ws + OFF_CMAX);

    init_kernel<<<1, 64, 0, stream>>>(cmaxu, out);
    norm_kernel<<<NN + MM, 64, 0, stream>>>(src, tgt, srcn, srcb, tgtb, tgtT);
    dot_kernel<<<(NN/64)*(MM/64), 256, 0, stream>>>(srcb, tgtb, Kq, cmaxu);
    for (int k = 0; k < NIT; ++k) {
        upass_kernel<<<NN/32, 512, 0, stream>>>(Kq, v, u, cmaxu, k == 0 ? 1 : 0);
        colpart_kernel<<<NN/32, 512, 0, stream>>>(Kq, u, part, cmaxu);
        vred_kernel<<<MM/64, 512, 0, stream>>>(part, v);
    }
    wt_kernel<<<512, 256, 0, stream>>>(tgtT, v, WT);
    final_kernel<<<NN/32, 512, 0, stream>>>(Kq, u, v, WT, srcn, cmaxu, out);
}

// Round 6
// 678.370 us; speedup vs baseline: 3.8410x; 1.1848x over previous
//
#include <hip/hip_runtime.h>
#include <hip/hip_bf16.h>
#include <stdint.h>

// Problem constants
#define NN 8192
#define MM 4096
#define DD 256
#define REGC 0.1f
#define FIC 0.8333333333333334f   // tau/(tau+reg) = 0.5/0.6
#define AMARG (1.0f/8192.0f)
#define BMARG (1.0f/4096.0f)
#define NIT 20                    // 0.694^20 * 8.3 ~ 6e-3 << 2% K-quantization error
#define QSCALE 63.75f             // u8 code: q = round(C * 63.75), C in [0,4]
#define QINV   0.01568627f        // 1/63.75
#define SINK_SMEM (131072 + 16384 + 128)   // Kq slab(32x4096) + v(4096 f32) + u(32 f32)

typedef __bf16 bf16x8_t __attribute__((ext_vector_type(8)));
typedef float f32x4_t __attribute__((ext_vector_type(4)));
typedef unsigned short us8_t __attribute__((ext_vector_type(8)));

__device__ __forceinline__ unsigned short f2bf(float f) {
    unsigned int u = __float_as_uint(f);
    u = u + 0x7FFFu + ((u >> 16) & 1u);   // RNE
    return (unsigned short)(u >> 16);
}
__device__ __forceinline__ float wsum(float v) {
    #pragma unroll
    for (int m = 32; m >= 1; m >>= 1) v += __shfl_xor(v, m, 64);
    return v;
}
__device__ __forceinline__ float wmaxr(float v) {
    #pragma unroll
    for (int m = 32; m >= 1; m >>= 1) v = fmaxf(v, __shfl_xor(v, m, 64));
    return v;
}
// acc += K(4 codes) . v4
__device__ __forceinline__ float dot4q(unsigned int kk, f32x4_t v, float negdec) {
    float s;
    s  = __expf((float)( kk        & 255u) * negdec) * v[0];
    s += __expf((float)((kk >> 8)  & 255u) * negdec) * v[1];
    s += __expf((float)((kk >> 16) & 255u) * negdec) * v[2];
    s += __expf((float)( kk >> 24        ) * negdec) * v[3];
    return s;
}
// col-pass: t[0..3] += K * uu for 4 codes
__device__ __forceinline__ void colacc4(unsigned int kk, float uu, float negdec, float* t) {
    t[0] += __expf((float)( kk        & 255u) * negdec) * uu;
    t[1] += __expf((float)((kk >> 8)  & 255u) * negdec) * uu;
    t[2] += __expf((float)((kk >> 16) & 255u) * negdec) * uu;
    t[3] += __expf((float)( kk >> 24        ) * negdec) * uu;
}

// ---------------- init: zero cmax + dist slot ----------------
__global__ void init_kernel(unsigned int* __restrict__ cmaxu, float* __restrict__ out) {
    if (threadIdx.x == 0) { *cmaxu = 0u; out[(size_t)NN*DD] = 0.0f; }
}

// ---------------- normalize rows; emit srcn(f32) + srcb/tgtb(bf16) + tgtT(bf16) ----------------
__global__ void norm_kernel(const float* __restrict__ src, const float* __restrict__ tgt,
                            float* __restrict__ srcn,
                            unsigned short* __restrict__ srcb, unsigned short* __restrict__ tgtb,
                            unsigned short* __restrict__ tgtT) {
    int b = blockIdx.x, l = threadIdx.x;      // 64 threads = 1 wave per row
    bool is_src = b < NN;
    int r = is_src ? b : b - NN;
    const float* in = is_src ? src : tgt;
    unsigned short* outb = is_src ? srcb : tgtb;

    f32x4_t x = *(const f32x4_t*)(in + (size_t)r*DD + l*4);
    float s = x[0]+x[1]+x[2]+x[3];
    s = wsum(s);
    float mean = s * (1.0f/(float)DD);
    float c0=x[0]-mean, c1=x[1]-mean, c2=x[2]-mean, c3=x[3]-mean;
    float ss = c0*c0+c1*c1+c2*c2+c3*c3;
    ss = wsum(ss);
    float scale = 1.0f / fmaxf(sqrtf(ss), 1e-8f);
    f32x4_t o; o[0]=c0*scale; o[1]=c1*scale; o[2]=c2*scale; o[3]=c3*scale;
    unsigned short b0=f2bf(o[0]), b1=f2bf(o[1]), b2=f2bf(o[2]), b3=f2bf(o[3]);
    unsigned long long pk = (unsigned long long)b0 | ((unsigned long long)b1<<16)
                          | ((unsigned long long)b2<<32) | ((unsigned long long)b3<<48);
    *(unsigned long long*)(outb + (size_t)r*DD + l*4) = pk;
    if (is_src) {
        *(f32x4_t*)(srcn + (size_t)r*DD + l*4) = o;
    } else {
        tgtT[(size_t)(l*4+0)*MM + r] = b0;
        tgtT[(size_t)(l*4+1)*MM + r] = b1;
        tgtT[(size_t)(l*4+2)*MM + r] = b2;
        tgtT[(size_t)(l*4+3)*MM + r] = b3;
    }
}

// ---------------- dots = srcn @ tgtn^T (MFMA bf16) -> u8 cost codes + global max cost ----------------
__launch_bounds__(256)
__global__ void dot_kernel(const unsigned short* __restrict__ srcb,
                           const unsigned short* __restrict__ tgtb,
                           unsigned char* __restrict__ Kq,
                           unsigned int* __restrict__ cmaxu) {
    __shared__ unsigned short Al[64][40];
    __shared__ unsigned short Bl[64][40];
    __shared__ float redsh[4];
    int tid = threadIdx.x;
    int bi = blockIdx.x & 127, bj = blockIdx.x >> 7;
    int i0 = bi * 64, j0 = bj * 64;
    int l = tid & 63, wid = tid >> 6;
    int wm = wid >> 1, wn = wid & 1;
    int fr = l & 15, kc = (l >> 4) * 8;
    f32x4_t acc[2][2] = {};
    int sr = tid >> 2, sc = (tid & 3) * 8;
    for (int kk = 0; kk < DD; kk += 32) {
        __syncthreads();
        *(uint4*)(&Al[sr][sc]) = *(const uint4*)(srcb + (size_t)(i0+sr)*DD + kk + sc);
        *(uint4*)(&Bl[sr][sc]) = *(const uint4*)(tgtb + (size_t)(j0+sr)*DD + kk + sc);
        __syncthreads();
        bf16x8_t a0 = *(const bf16x8_t*)(&Al[wm*32 + fr][kc]);
        bf16x8_t a1 = *(const bf16x8_t*)(&Al[wm*32 + 16 + fr][kc]);
        bf16x8_t b0 = *(const bf16x8_t*)(&Bl[wn*32 + fr][kc]);
        bf16x8_t b1 = *(const bf16x8_t*)(&Bl[wn*32 + 16 + fr][kc]);
        acc[0][0] = __builtin_amdgcn_mfma_f32_16x16x32_bf16(a0, b0, acc[0][0], 0, 0, 0);
        acc[0][1] = __builtin_amdgcn_mfma_f32_16x16x32_bf16(a0, b1, acc[0][1], 0, 0, 0);
        acc[1][0] = __builtin_amdgcn_mfma_f32_16x16x32_bf16(a1, b0, acc[1][0], 0, 0, 0);
        acc[1][1] = __builtin_amdgcn_mfma_f32_16x16x32_bf16(a1, b1, acc[1][1], 0, 0, 0);
    }
    int rq = (l >> 4) * 4;
    float mx = 0.0f;
    #pragma unroll
    for (int fm = 0; fm < 2; ++fm) {
        #pragma unroll
        for (int fn = 0; fn < 2; ++fn) {
            #pragma unroll
            for (int q = 0; q < 4; ++q) {
                int row = i0 + wm*32 + fm*16 + rq + q;
                int col = j0 + wn*32 + fn*16 + fr;
                float C = fmaxf(2.0f - 2.0f*acc[fm][fn][q], 0.0f);
                mx = fmaxf(mx, C);
                Kq[(size_t)row*MM + col] =
                    (unsigned char)(fminf(C*QSCALE, 255.0f) + 0.5f);
            }
        }
    }
    mx = wmaxr(mx);
    if (l == 0) redsh[wid] = mx;
    __syncthreads();
    if (tid == 0) {
        float m = fmaxf(fmaxf(redsh[0], redsh[1]), fmaxf(redsh[2], redsh[3]));
        atomicMax(cmaxu, __float_as_uint(m));
    }
}

// ---------------- fused Sinkhorn iteration: stage Kq slab -> LDS; u-pass; col-partials ----
// 256 blocks x 512 thr; block = 32 rows, K slab 128 KB in LDS (read from global ONCE/iter).
// Phase A: wave w -> rows 4w..4w+3; lane l -> cols l*4+256s+1024c (conflict-free b32).
// Phase B: wave w -> cols [w*512,w*512+512); lane l -> 8 cols (conflict-free b64).
__launch_bounds__(512)
__global__ void sink_kernel(const unsigned char* __restrict__ Kq,
                            const float* __restrict__ vin,
                            float* __restrict__ uout,
                            float* __restrict__ part,
                            const unsigned int* __restrict__ cmaxu,
                            int first) {
    extern __shared__ unsigned char smem[];
    unsigned char* Kl = smem;                    // [32*4096] u8
    float* v_lds = (float*)(smem + 131072);      // [4096]
    float* u_lds = v_lds + MM;                   // [32]
    int tid = threadIdx.x, l = tid & 63, w = tid >> 6;
    int row0 = blockIdx.x * 32;
    float negdec = -0.15686275f / __uint_as_float(*cmaxu);   // -1/(63.75*REG*cmax)

    // stage the 128 KB slab (16 uint4 per thread, linear)
    {
        const uint4* sp = (const uint4*)(Kq + (size_t)row0*MM);
        uint4* dp = (uint4*)Kl;
        #pragma unroll
        for (int q = 0; q < 16; ++q) dp[q*512 + tid] = sp[q*512 + tid];
    }
    if (first) {
        #pragma unroll
        for (int q = 0; q < 8; ++q) v_lds[tid*8 + q] = 1.0f;
    } else {
        f32x4_t a0 = *(const f32x4_t*)(vin + tid*8);
        f32x4_t a1 = *(const f32x4_t*)(vin + tid*8 + 4);
        *(f32x4_t*)(v_lds + tid*8) = a0;
        *(f32x4_t*)(v_lds + tid*8 + 4) = a1;
    }
    __syncthreads();

    // ---- Phase A: row sums -> u
    f32x4_t vr[4][4];
    #pragma unroll
    for (int c = 0; c < 4; ++c)
        #pragma unroll
        for (int s = 0; s < 4; ++s)
            vr[c][s] = *(const f32x4_t*)(v_lds + c*1024 + s*256 + l*4);
    int rbase = 4*w;
    float racc[4];
    #pragma unroll
    for (int r = 0; r < 4; ++r) {
        const unsigned char* Kr = Kl + (size_t)(rbase + r)*MM + l*4;
        unsigned int code[16];
        #pragma unroll
        for (int c = 0; c < 4; ++c)
            #pragma unroll
            for (int s = 0; s < 4; ++s)
                code[c*4+s] = *(const unsigned int*)(Kr + c*1024 + s*256);
        float acc = 0.0f;
        #pragma unroll
        for (int c = 0; c < 4; ++c)
            #pragma unroll
            for (int s = 0; s < 4; ++s)
                acc += dot4q(code[c*4+s], vr[c][s], negdec);
        racc[r] = wsum(acc);
    }
    float sel = racc[0];
    if (l == 1) sel = racc[1];
    if (l == 2) sel = racc[2];
    if (l == 3) sel = racc[3];
    float uu = __expf(FIC * __logf(AMARG / sel));
    if (l < 4) {
        u_lds[rbase + l] = uu;
        uout[row0 + rbase + l] = uu;
    }
    __syncthreads();

    // ---- Phase B: col partials
    int jb = w*512 + l*8;
    const unsigned char* Kp = Kl + jb;
    float tacc[8] = {0.f,0.f,0.f,0.f,0.f,0.f,0.f,0.f};
    #pragma unroll
    for (int g = 0; g < 4; ++g) {
        uint2 cc[8];
        #pragma unroll
        for (int r = 0; r < 8; ++r)
            cc[r] = *(const uint2*)(Kp + (size_t)(g*8 + r)*MM);
        #pragma unroll
        for (int r = 0; r < 8; ++r) {
            float ur = u_lds[g*8 + r];
            colacc4(cc[r].x, ur, negdec, &tacc[0]);
            colacc4(cc[r].y, ur, negdec, &tacc[4]);
        }
    }
    float* pp = part + (size_t)blockIdx.x*MM + jb;
    f32x4_t o0; o0[0]=tacc[0]; o0[1]=tacc[1]; o0[2]=tacc[2]; o0[3]=tacc[3];
    f32x4_t o1; o1[0]=tacc[4]; o1[1]=tacc[5]; o1[2]=tacc[6]; o1[3]=tacc[7];
    *(f32x4_t*)pp = o0;
    *(f32x4_t*)(pp + 4) = o1;
}

// ---------------- v-reduce: v_j = (b / sum_p part[p][j])^fi  (256 partials) ----------------
__launch_bounds__(512)
__global__ void vred_kernel(const float* __restrict__ part, float* __restrict__ vout) {
    __shared__ float red[8][64];
    int tid = threadIdx.x, l = tid & 63, w = tid >> 6;
    int j = blockIdx.x * 64 + l;
    float s = 0.0f;
    #pragma unroll 8
    for (int p = w*32; p < w*32 + 32; ++p) s += part[(size_t)p*MM + j];
    red[w][l] = s;
    __syncthreads();
    if (w == 0) {
        float t = red[0][l];
        #pragma unroll
        for (int ww = 1; ww < 8; ++ww) t += red[ww][l];
        vout[j] = __expf(FIC * __logf(BMARG / t));
    }
}

// ---------------- WT[d][j] = v_j * tgtT[d][j] (bf16) ----------------
__global__ void wt_kernel(const unsigned short* __restrict__ tgtT,
                          const float* __restrict__ v,
                          unsigned short* __restrict__ WT) {
    int idx = blockIdx.x * 256 + threadIdx.x;   // 512 blocks x 256 thr
    int d = idx >> 9, jc = (idx & 511) * 8;
    us8_t tv = *(const us8_t*)(tgtT + (size_t)d*MM + jc);
    f32x4_t v0 = *(const f32x4_t*)(v + jc);
    f32x4_t v1 = *(const f32x4_t*)(v + jc + 4);
    us8_t o;
    #pragma unroll
    for (int q = 0; q < 8; ++q) {
        float vv = (q < 4) ? v0[q] : v1[q-4];
        float kf = __uint_as_float(((unsigned int)tv[q]) << 16);
        o[q] = f2bf(kf * vv);
    }
    *(us8_t*)(WT + (size_t)d*MM + jc) = o;
}

// ---------------- finalize: out = srcn + diag(u)*(K @ WT^T); dist spread across waves ----
// 256 blocks x 512 thr; block = 32 rows; wave = 2 d-frags x 2 row-halves; prefetched codes.
__launch_bounds__(512)
__global__ void final_kernel(const unsigned char* __restrict__ Kq,
                             const float* __restrict__ u,
                             const float* __restrict__ v,
                             const unsigned short* __restrict__ WT,
                             const float* __restrict__ srcn,
                             const unsigned int* __restrict__ cmaxu,
                             float* __restrict__ out) {
    __shared__ float dsh[8];
    int tid = threadIdx.x, l = tid & 63, w = tid >> 6;
    int i0 = blockIdx.x * 32;
    int fr = l & 15, kq8 = (l >> 4) * 8;
    float negdec = -0.15686275f / __uint_as_float(*cmaxu);
    float u_h0 = u[i0 + fr], u_h1 = u[i0 + 16 + fr];
    const unsigned char* K0 = Kq + (size_t)(i0 + fr)*MM;
    const unsigned char* K1 = Kq + (size_t)(i0 + 16 + fr)*MM;
    f32x4_t acc[2][2] = {};
    float distp = 0.0f;
    uint2 c0 = *(const uint2*)(K0 + kq8);
    uint2 c1 = *(const uint2*)(K1 + kq8);
    for (int jc = 0; jc < MM; jc += 32) {
        int off = jc + kq8;
        // prefetch next step's codes (last-iter read is harmlessly in-bounds of ws)
        uint2 n0 = *(const uint2*)(K0 + off + 32);
        uint2 n1 = *(const uint2*)(K1 + off + 32);
        bf16x8_t afr[2];
        bool mine = ((jc >> 9) == w);      // this wave's dist strip
        #pragma unroll
        for (int h = 0; h < 2; ++h) {
            uint2 kk = h ? c1 : c0;
            float q0 = (float)( kk.x        & 255u);
            float q1 = (float)((kk.x >> 8)  & 255u);
            float q2 = (float)((kk.x >> 16) & 255u);
            float q3 = (float)( kk.x >> 24        );
            float q4 = (float)( kk.y        & 255u);
            float q5 = (float)((kk.y >> 8)  & 255u);
            float q6 = (float)((kk.y >> 16) & 255u);
            float q7 = (float)( kk.y >> 24        );
            float f0 = __expf(q0*negdec), f1 = __expf(q1*negdec);
            float f2 = __expf(q2*negdec), f3 = __expf(q3*negdec);
            float f4 = __expf(q4*negdec), f5 = __expf(q5*negdec);
            float f6 = __expf(q6*negdec), f7 = __expf(q7*negdec);
            if (mine) {
                f32x4_t va = *(const f32x4_t*)(v + off);
                f32x4_t vb = *(const f32x4_t*)(v + off + 4);
                float uh = h ? u_h1 : u_h0;
                float d = q0*f0*va[0] + q1*f1*va[1] + q2*f2*va[2] + q3*f3*va[3]
                        + q4*f4*vb[0] + q5*f5*vb[1] + q6*f6*vb[2] + q7*f7*vb[3];
                distp += uh * d;
            }
            uint4 pk;
            asm("v_cvt_pk_bf16_f32 %0, %1, %2" : "=v"(pk.x) : "v"(f0), "v"(f1));
            asm("v_cvt_pk_bf16_f32 %0, %1, %2" : "=v"(pk.y) : "v"(f2), "v"(f3));
            asm("v_cvt_pk_bf16_f32 %0, %1, %2" : "=v"(pk.z) : "v"(f4), "v"(f5));
            asm("v_cvt_pk_bf16_f32 %0, %1, %2" : "=v"(pk.w) : "v"(f6), "v"(f7));
            afr[h] = __builtin_bit_cast(bf16x8_t, pk);
        }
        #pragma unroll
        for (int b = 0; b < 2; ++b) {
            int drow = (2*w + b)*16 + fr;
            bf16x8_t bfr = *(const bf16x8_t*)(WT + (size_t)drow*MM + off);
            acc[0][b] = __builtin_amdgcn_mfma_f32_16x16x32_bf16(afr[0], bfr, acc[0][b], 0, 0, 0);
            acc[1][b] = __builtin_amdgcn_mfma_f32_16x16x32_bf16(afr[1], bfr, acc[1][b], 0, 0, 0);
        }
        c0 = n0; c1 = n1;
    }
    int rq = (l >> 4) * 4;
    #pragma unroll
    for (int h = 0; h < 2; ++h) {
        #pragma unroll
        for (int qq = 0; qq < 4; ++qq) {
            int i = i0 + h*16 + rq + qq;
            float uu = u[i];
            #pragma unroll
            for (int b = 0; b < 2; ++b) {
                int d = (2*w + b)*16 + fr;
                size_t idx = (size_t)i*DD + d;
                out[idx] = srcn[idx] + uu*acc[h][b][qq];
            }
        }
    }
    distp = wsum(distp);
    if (l == 0) dsh[w] = distp;
    __syncthreads();
    if (tid == 0) {
        float t = 0.0f;
        #pragma unroll
        for (int ww = 0; ww < 8; ++ww) t += dsh[ww];
        atomicAdd(out + (size_t)NN*DD, t * QINV);
    }
}

// ---------------- host ----------------
extern "C" void kernel_launch(void* const* d_in, const int* in_sizes, int n_in,
                              void* d_out, int out_size, void* d_ws, size_t ws_size,
                              hipStream_t stream) {
    const float* src = (const float*)d_in[0];
    const float* tgt = (const float*)d_in[1];
    float* out = (float*)d_out;
    char* ws = (char*)d_ws;

    constexpr size_t OFF_SRCN = 0;                        // 8192*256*4  = 8388608
    constexpr size_t OFF_SRCB = 8388608;                  // 8192*256*2  = 4194304
    constexpr size_t OFF_TGTB = 12582912;                 // 4096*256*2  = 2097152
    constexpr size_t OFF_TGTT = 14680064;                 // 256*4096*2  = 2097152
    constexpr size_t OFF_WT   = 16777216;                 // 256*4096*2  = 2097152
    constexpr size_t OFF_KQ   = 18874368;                 // 8192*4096*1 = 33554432
    constexpr size_t OFF_PART = 52428800;                 // 256*4096*4  = 4194304
    constexpr size_t OFF_U    = 56623104;                 // 8192*4
    constexpr size_t OFF_V    = 56655872;                 // 4096*4
    constexpr size_t OFF_CMAX = 56672256;                 // 4

    float* srcn = (float*)(ws + OFF_SRCN);
    unsigned short* srcb = (unsigned short*)(ws + OFF_SRCB);
    unsigned short* tgtb = (unsigned short*)(ws + OFF_TGTB);
    unsigned short* tgtT = (unsigned short*)(ws + OFF_TGTT);
    unsigned short* WT   = (unsigned short*)(ws + OFF_WT);
    unsigned char* Kq    = (unsigned char*)(ws + OFF_KQ);
    float* part = (float*)(ws + OFF_PART);
    float* u    = (float*)(ws + OFF_U);
    float* v    = (float*)(ws + OFF_V);
    unsigned int* cmaxu = (unsigned int*)(ws + OFF_CMAX);

    static int attr_done = 0;
    if (!attr_done) {
        (void)hipFuncSetAttribute((const void*)sink_kernel,
                                  hipFuncAttributeMaxDynamicSharedMemorySize,
                                  SINK_SMEM);
        attr_done = 1;
    }

    init_kernel<<<1, 64, 0, stream>>>(cmaxu, out);
    norm_kernel<<<NN + MM, 64, 0, stream>>>(src, tgt, srcn, srcb, tgtb, tgtT);
    dot_kernel<<<(NN/64)*(MM/64), 256, 0, stream>>>(srcb, tgtb, Kq, cmaxu);
    for (int k = 0; k < NIT; ++k) {
        sink_kernel<<<NN/32, 512, SINK_SMEM, stream>>>(Kq, v, u, part, cmaxu, k == 0 ? 1 : 0);
        vred_kernel<<<MM/64, 512, 0, stream>>>(part, v);
    }
    wt_kernel<<<512, 256, 0, stream>>>(tgtT, v, WT);
    final_kernel<<<NN/32, 512, 0, stream>>>(Kq, u, v, WT, srcn, cmaxu, out);
}

// Round 7
// 546.136 us; speedup vs baseline: 4.7710x; 1.2421x over previous
//
#include <hip/hip_runtime.h>
#include <hip/hip_bf16.h>
#include <stdint.h>

// Problem constants
#define NN 8192
#define MM 4096
#define DD 256
#define REGC 0.1f
#define FIC 0.8333333333333334f   // tau/(tau+reg) = 0.5/0.6
#define AMARG (1.0f/8192.0f)
#define BMARG (1.0f/4096.0f)
#define NIT 16                    // absmax invariant 250->20; contraction margin ample
#define QSCALE 63.75f             // u8 code: q = round(C * 63.75), C in [0,4]
#define QINV   0.01568627f        // 1/63.75
#define SINK_SMEM (131072 + 16384 + 128)   // Kq slab(32x4096) + v(4096 f32) + u(32 f32)
#define FIN_SMEM  65536                    // P double buffer: 2 x 32 KB

typedef __bf16 bf16x8_t __attribute__((ext_vector_type(8)));
typedef float f32x4_t __attribute__((ext_vector_type(4)));
typedef unsigned short us8_t __attribute__((ext_vector_type(8)));

__device__ __forceinline__ unsigned short f2bf(float f) {
    unsigned int u = __float_as_uint(f);
    u = u + 0x7FFFu + ((u >> 16) & 1u);   // RNE
    return (unsigned short)(u >> 16);
}
__device__ __forceinline__ float wsum(float v) {
    #pragma unroll
    for (int m = 32; m >= 1; m >>= 1) v += __shfl_xor(v, m, 64);
    return v;
}
__device__ __forceinline__ float wmaxr(float v) {
    #pragma unroll
    for (int m = 32; m >= 1; m >>= 1) v = fmaxf(v, __shfl_xor(v, m, 64));
    return v;
}
// acc += K(4 codes) . v4
__device__ __forceinline__ float dot4q(unsigned int kk, f32x4_t v, float negdec) {
    float s;
    s  = __expf((float)( kk        & 255u) * negdec) * v[0];
    s += __expf((float)((kk >> 8)  & 255u) * negdec) * v[1];
    s += __expf((float)((kk >> 16) & 255u) * negdec) * v[2];
    s += __expf((float)( kk >> 24        ) * negdec) * v[3];
    return s;
}
// col-pass: t[0..3] += K * uu for 4 codes
__device__ __forceinline__ void colacc4(unsigned int kk, float uu, float negdec, float* t) {
    t[0] += __expf((float)( kk        & 255u) * negdec) * uu;
    t[1] += __expf((float)((kk >> 8)  & 255u) * negdec) * uu;
    t[2] += __expf((float)((kk >> 16) & 255u) * negdec) * uu;
    t[3] += __expf((float)( kk >> 24        ) * negdec) * uu;
}

// decode 16 codes (one uint4) of row (ri,fr), strip-local k-frag kf, kq pair base kqb;
// write two swizzled bf16x8 fragments into buf; return dist contribution (scaled by u_r).
__device__ __forceinline__ float decode16(uint4 kk, int ri, int fr, int kf, int kqb,
                                          const float* __restrict__ vp,
                                          float u_r, float negdec,
                                          unsigned char* __restrict__ buf) {
    float q[16], f[16];
    unsigned int wv[4] = {kk.x, kk.y, kk.z, kk.w};
    #pragma unroll
    for (int a = 0; a < 4; ++a) {
        unsigned int k = wv[a];
        q[a*4+0] = (float)( k        & 255u);
        q[a*4+1] = (float)((k >> 8)  & 255u);
        q[a*4+2] = (float)((k >> 16) & 255u);
        q[a*4+3] = (float)( k >> 24        );
    }
    #pragma unroll
    for (int e = 0; e < 16; ++e) f[e] = __expf(q[e] * negdec);
    float d = 0.0f;
    #pragma unroll
    for (int a = 0; a < 4; ++a) {
        f32x4_t vv = *(const f32x4_t*)(vp + a*4);
        d += q[a*4+0]*f[a*4+0]*vv[0] + q[a*4+1]*f[a*4+1]*vv[1]
           + q[a*4+2]*f[a*4+2]*vv[2] + q[a*4+3]*f[a*4+3]*vv[3];
    }
    uint4 p0, p1;
    asm("v_cvt_pk_bf16_f32 %0, %1, %2" : "=v"(p0.x) : "v"(f[0]),  "v"(f[1]));
    asm("v_cvt_pk_bf16_f32 %0, %1, %2" : "=v"(p0.y) : "v"(f[2]),  "v"(f[3]));
    asm("v_cvt_pk_bf16_f32 %0, %1, %2" : "=v"(p0.z) : "v"(f[4]),  "v"(f[5]));
    asm("v_cvt_pk_bf16_f32 %0, %1, %2" : "=v"(p0.w) : "v"(f[6]),  "v"(f[7]));
    asm("v_cvt_pk_bf16_f32 %0, %1, %2" : "=v"(p1.x) : "v"(f[8]),  "v"(f[9]));
    asm("v_cvt_pk_bf16_f32 %0, %1, %2" : "=v"(p1.y) : "v"(f[10]), "v"(f[11]));
    asm("v_cvt_pk_bf16_f32 %0, %1, %2" : "=v"(p1.z) : "v"(f[12]), "v"(f[13]));
    asm("v_cvt_pk_bf16_f32 %0, %1, %2" : "=v"(p1.w) : "v"(f[14]), "v"(f[15]));
    int base = ri*16384 + kf*1024;
    *(uint4*)(buf + base + (((kqb    )*16 + fr) ^ (kf & 7))*16) = p0;
    *(uint4*)(buf + base + (((kqb + 1)*16 + fr) ^ (kf & 7))*16) = p1;
    return d * u_r;
}

// ---------------- init: zero cmax + dist slot ----------------
__global__ void init_kernel(unsigned int* __restrict__ cmaxu, float* __restrict__ out) {
    if (threadIdx.x == 0) { *cmaxu = 0u; out[(size_t)NN*DD] = 0.0f; }
}

// ---------------- normalize rows; emit srcn(f32) + srcb/tgtb(bf16) + tgtT(bf16) ----------------
__global__ void norm_kernel(const float* __restrict__ src, const float* __restrict__ tgt,
                            float* __restrict__ srcn,
                            unsigned short* __restrict__ srcb, unsigned short* __restrict__ tgtb,
                            unsigned short* __restrict__ tgtT) {
    int b = blockIdx.x, l = threadIdx.x;      // 64 threads = 1 wave per row
    bool is_src = b < NN;
    int r = is_src ? b : b - NN;
    const float* in = is_src ? src : tgt;
    unsigned short* outb = is_src ? srcb : tgtb;

    f32x4_t x = *(const f32x4_t*)(in + (size_t)r*DD + l*4);
    float s = x[0]+x[1]+x[2]+x[3];
    s = wsum(s);
    float mean = s * (1.0f/(float)DD);
    float c0=x[0]-mean, c1=x[1]-mean, c2=x[2]-mean, c3=x[3]-mean;
    float ss = c0*c0+c1*c1+c2*c2+c3*c3;
    ss = wsum(ss);
    float scale = 1.0f / fmaxf(sqrtf(ss), 1e-8f);
    f32x4_t o; o[0]=c0*scale; o[1]=c1*scale; o[2]=c2*scale; o[3]=c3*scale;
    unsigned short b0=f2bf(o[0]), b1=f2bf(o[1]), b2=f2bf(o[2]), b3=f2bf(o[3]);
    unsigned long long pk = (unsigned long long)b0 | ((unsigned long long)b1<<16)
                          | ((unsigned long long)b2<<32) | ((unsigned long long)b3<<48);
    *(unsigned long long*)(outb + (size_t)r*DD + l*4) = pk;
    if (is_src) {
        *(f32x4_t*)(srcn + (size_t)r*DD + l*4) = o;
    } else {
        tgtT[(size_t)(l*4+0)*MM + r] = b0;
        tgtT[(size_t)(l*4+1)*MM + r] = b1;
        tgtT[(size_t)(l*4+2)*MM + r] = b2;
        tgtT[(size_t)(l*4+3)*MM + r] = b3;
    }
}

// ---------------- dots = srcn @ tgtn^T (MFMA bf16) -> u8 cost codes + global max cost ----------------
__launch_bounds__(256)
__global__ void dot_kernel(const unsigned short* __restrict__ srcb,
                           const unsigned short* __restrict__ tgtb,
                           unsigned char* __restrict__ Kq,
                           unsigned int* __restrict__ cmaxu) {
    __shared__ unsigned short Al[64][40];
    __shared__ unsigned short Bl[64][40];
    __shared__ float redsh[4];
    int tid = threadIdx.x;
    int bi = blockIdx.x & 127, bj = blockIdx.x >> 7;
    int i0 = bi * 64, j0 = bj * 64;
    int l = tid & 63, wid = tid >> 6;
    int wm = wid >> 1, wn = wid & 1;
    int fr = l & 15, kc = (l >> 4) * 8;
    f32x4_t acc[2][2] = {};
    int sr = tid >> 2, sc = (tid & 3) * 8;
    for (int kk = 0; kk < DD; kk += 32) {
        __syncthreads();
        *(uint4*)(&Al[sr][sc]) = *(const uint4*)(srcb + (size_t)(i0+sr)*DD + kk + sc);
        *(uint4*)(&Bl[sr][sc]) = *(const uint4*)(tgtb + (size_t)(j0+sr)*DD + kk + sc);
        __syncthreads();
        bf16x8_t a0 = *(const bf16x8_t*)(&Al[wm*32 + fr][kc]);
        bf16x8_t a1 = *(const bf16x8_t*)(&Al[wm*32 + 16 + fr][kc]);
        bf16x8_t b0 = *(const bf16x8_t*)(&Bl[wn*32 + fr][kc]);
        bf16x8_t b1 = *(const bf16x8_t*)(&Bl[wn*32 + 16 + fr][kc]);
        acc[0][0] = __builtin_amdgcn_mfma_f32_16x16x32_bf16(a0, b0, acc[0][0], 0, 0, 0);
        acc[0][1] = __builtin_amdgcn_mfma_f32_16x16x32_bf16(a0, b1, acc[0][1], 0, 0, 0);
        acc[1][0] = __builtin_amdgcn_mfma_f32_16x16x32_bf16(a1, b0, acc[1][0], 0, 0, 0);
        acc[1][1] = __builtin_amdgcn_mfma_f32_16x16x32_bf16(a1, b1, acc[1][1], 0, 0, 0);
    }
    int rq = (l >> 4) * 4;
    float mx = 0.0f;
    #pragma unroll
    for (int fm = 0; fm < 2; ++fm) {
        #pragma unroll
        for (int fn = 0; fn < 2; ++fn) {
            #pragma unroll
            for (int q = 0; q < 4; ++q) {
                int row = i0 + wm*32 + fm*16 + rq + q;
                int col = j0 + wn*32 + fn*16 + fr;
                float C = fmaxf(2.0f - 2.0f*acc[fm][fn][q], 0.0f);
                mx = fmaxf(mx, C);
                Kq[(size_t)row*MM + col] =
                    (unsigned char)(fminf(C*QSCALE, 255.0f) + 0.5f);
            }
        }
    }
    mx = wmaxr(mx);
    if (l == 0) redsh[wid] = mx;
    __syncthreads();
    if (tid == 0) {
        float m = fmaxf(fmaxf(redsh[0], redsh[1]), fmaxf(redsh[2], redsh[3]));
        atomicMax(cmaxu, __float_as_uint(m));
    }
}

// ---------------- fused Sinkhorn iteration: stage Kq slab -> LDS; u-pass; col-partials ----
__launch_bounds__(512)
__global__ void sink_kernel(const unsigned char* __restrict__ Kq,
                            const float* __restrict__ vin,
                            float* __restrict__ uout,
                            float* __restrict__ part,
                            const unsigned int* __restrict__ cmaxu,
                            int first) {
    extern __shared__ unsigned char smem[];
    unsigned char* Kl = smem;                    // [32*4096] u8
    float* v_lds = (float*)(smem + 131072);      // [4096]
    float* u_lds = v_lds + MM;                   // [32]
    int tid = threadIdx.x, l = tid & 63, w = tid >> 6;
    int row0 = blockIdx.x * 32;
    float negdec = -0.15686275f / __uint_as_float(*cmaxu);   // -1/(63.75*REG*cmax)

    // stage the 128 KB slab (16 uint4 per thread, linear)
    {
        const uint4* sp = (const uint4*)(Kq + (size_t)row0*MM);
        uint4* dp = (uint4*)Kl;
        #pragma unroll
        for (int q = 0; q < 16; ++q) dp[q*512 + tid] = sp[q*512 + tid];
    }
    if (first) {
        #pragma unroll
        for (int q = 0; q < 8; ++q) v_lds[tid*8 + q] = 1.0f;
    } else {
        f32x4_t a0 = *(const f32x4_t*)(vin + tid*8);
        f32x4_t a1 = *(const f32x4_t*)(vin + tid*8 + 4);
        *(f32x4_t*)(v_lds + tid*8) = a0;
        *(f32x4_t*)(v_lds + tid*8 + 4) = a1;
    }
    __syncthreads();

    // ---- Phase A: row sums -> u
    f32x4_t vr[4][4];
    #pragma unroll
    for (int c = 0; c < 4; ++c)
        #pragma unroll
        for (int s = 0; s < 4; ++s)
            vr[c][s] = *(const f32x4_t*)(v_lds + c*1024 + s*256 + l*4);
    int rbase = 4*w;
    float racc[4];
    #pragma unroll
    for (int r = 0; r < 4; ++r) {
        const unsigned char* Kr = Kl + (size_t)(rbase + r)*MM + l*4;
        unsigned int code[16];
        #pragma unroll
        for (int c = 0; c < 4; ++c)
            #pragma unroll
            for (int s = 0; s < 4; ++s)
                code[c*4+s] = *(const unsigned int*)(Kr + c*1024 + s*256);
        float acc = 0.0f;
        #pragma unroll
        for (int c = 0; c < 4; ++c)
            #pragma unroll
            for (int s = 0; s < 4; ++s)
                acc += dot4q(code[c*4+s], vr[c][s], negdec);
        racc[r] = wsum(acc);
    }
    float sel = racc[0];
    if (l == 1) sel = racc[1];
    if (l == 2) sel = racc[2];
    if (l == 3) sel = racc[3];
    float uu = __expf(FIC * __logf(AMARG / sel));
    if (l < 4) {
        u_lds[rbase + l] = uu;
        uout[row0 + rbase + l] = uu;
    }
    __syncthreads();

    // ---- Phase B: col partials
    int jb = w*512 + l*8;
    const unsigned char* Kp = Kl + jb;
    float tacc[8] = {0.f,0.f,0.f,0.f,0.f,0.f,0.f,0.f};
    #pragma unroll
    for (int g = 0; g < 4; ++g) {
        uint2 cc[8];
        #pragma unroll
        for (int r = 0; r < 8; ++r)
            cc[r] = *(const uint2*)(Kp + (size_t)(g*8 + r)*MM);
        #pragma unroll
        for (int r = 0; r < 8; ++r) {
            float ur = u_lds[g*8 + r];
            colacc4(cc[r].x, ur, negdec, &tacc[0]);
            colacc4(cc[r].y, ur, negdec, &tacc[4]);
        }
    }
    float* pp = part + (size_t)blockIdx.x*MM + jb;
    f32x4_t o0; o0[0]=tacc[0]; o0[1]=tacc[1]; o0[2]=tacc[2]; o0[3]=tacc[3];
    f32x4_t o1; o1[0]=tacc[4]; o1[1]=tacc[5]; o1[2]=tacc[6]; o1[3]=tacc[7];
    *(f32x4_t*)pp = o0;
    *(f32x4_t*)(pp + 4) = o1;
}

// ---------------- v-reduce: v_j = (b / sum_p part[p][j])^fi  (256 partials) ----------------
__launch_bounds__(512)
__global__ void vred_kernel(const float* __restrict__ part, float* __restrict__ vout) {
    __shared__ float red[8][64];
    int tid = threadIdx.x, l = tid & 63, w = tid >> 6;
    int j = blockIdx.x * 64 + l;
    float s = 0.0f;
    #pragma unroll 8
    for (int p = w*32; p < w*32 + 32; ++p) s += part[(size_t)p*MM + j];
    red[w][l] = s;
    __syncthreads();
    if (w == 0) {
        float t = red[0][l];
        #pragma unroll
        for (int ww = 1; ww < 8; ++ww) t += red[ww][l];
        vout[j] = __expf(FIC * __logf(BMARG / t));
    }
}

// ---------------- WT[d][j] = v_j * tgtT[d][j] (bf16) ----------------
__global__ void wt_kernel(const unsigned short* __restrict__ tgtT,
                          const float* __restrict__ v,
                          unsigned short* __restrict__ WT) {
    int idx = blockIdx.x * 256 + threadIdx.x;   // 512 blocks x 256 thr
    int d = idx >> 9, jc = (idx & 511) * 8;
    us8_t tv = *(const us8_t*)(tgtT + (size_t)d*MM + jc);
    f32x4_t v0 = *(const f32x4_t*)(v + jc);
    f32x4_t v1 = *(const f32x4_t*)(v + jc + 4);
    us8_t o;
    #pragma unroll
    for (int q = 0; q < 8; ++q) {
        float vv = (q < 4) ? v0[q] : v1[q-4];
        float kf = __uint_as_float(((unsigned int)tv[q]) << 16);
        o[q] = f2bf(kf * vv);
    }
    *(us8_t*)(WT + (size_t)d*MM + jc) = o;
}

// ---------------- finalize: out = srcn + diag(u)*(K @ WT^T); decode-once via LDS ----------
// 256 blocks x 512 thr; block = 32 rows. Per 512-col strip: decode Kq->bf16 fragments in
// LDS (swizzled, conflict-free), double-buffered; 8 waves MFMA (wave w owns d 32w..32w+31).
// dist fused into decode (each element touched once chip-wide).
__launch_bounds__(512)
__global__ void final_kernel(const unsigned char* __restrict__ Kq,
                             const float* __restrict__ u,
                             const float* __restrict__ v,
                             const unsigned short* __restrict__ WT,
                             const float* __restrict__ srcn,
                             const unsigned int* __restrict__ cmaxu,
                             float* __restrict__ out) {
    extern __shared__ unsigned char smem[];   // [2][32768] P buffers
    __shared__ float dsh[8];
    int tid = threadIdx.x, l = tid & 63, w = tid >> 6;
    int i0 = blockIdx.x * 32;
    int fr = l & 15;
    float negdec = -0.15686275f / __uint_as_float(*cmaxu);

    // this thread's two decode chunks (16 codes each): ch = tid, tid+512
    int r0 = tid >> 5,          cc0 = (tid & 31) * 16;
    int r1 = (tid + 512) >> 5,  cc1 = ((tid + 512) & 31) * 16;
    int ri0 = r0 >> 4, fr0 = r0 & 15, kf0 = cc0 >> 5, kqb0 = (cc0 >> 3) & 3;
    int ri1 = r1 >> 4, fr1 = r1 & 15, kf1 = cc1 >> 5, kqb1 = (cc1 >> 3) & 3;
    const unsigned char* Kr0 = Kq + (size_t)(i0 + r0)*MM + cc0;
    const unsigned char* Kr1 = Kq + (size_t)(i0 + r1)*MM + cc1;
    float u_r0 = u[i0 + r0], u_r1 = u[i0 + r1];
    float distp = 0.0f;

    // prologue: decode strip 0 into buf 0
    {
        uint4 k0 = *(const uint4*)(Kr0);
        uint4 k1 = *(const uint4*)(Kr1);
        distp += decode16(k0, ri0, fr0, kf0, kqb0, v + cc0, u_r0, negdec, smem);
        distp += decode16(k1, ri1, fr1, kf1, kqb1, v + cc1, u_r1, negdec, smem);
    }
    __syncthreads();

    f32x4_t acc[2][2] = {};
    for (int s = 0; s < 8; ++s) {
        unsigned char* cur = smem + (s & 1) * 32768;
        unsigned char* nxt = smem + ((s + 1) & 1) * 32768;
        int jc0 = s * 512;
        uint4 n0, n1;
        if (s < 7) {                       // issue next-strip code loads early (T14)
            n0 = *(const uint4*)(Kr0 + (s + 1) * 512);
            n1 = *(const uint4*)(Kr1 + (s + 1) * 512);
        }
        #pragma unroll
        for (int kf = 0; kf < 16; ++kf) {
            int sl = (l ^ (kf & 7)) * 16;
            bf16x8_t a0 = *(const bf16x8_t*)(cur + kf*1024 + sl);
            bf16x8_t a1 = *(const bf16x8_t*)(cur + 16384 + kf*1024 + sl);
            int kofs = jc0 + kf*32 + (l >> 4) * 8;
            bf16x8_t b0 = *(const bf16x8_t*)(WT + (size_t)(32*w + fr)*MM + kofs);
            bf16x8_t b1 = *(const bf16x8_t*)(WT + (size_t)(32*w + 16 + fr)*MM + kofs);
            acc[0][0] = __builtin_amdgcn_mfma_f32_16x16x32_bf16(a0, b0, acc[0][0], 0, 0, 0);
            acc[0][1] = __builtin_amdgcn_mfma_f32_16x16x32_bf16(a0, b1, acc[0][1], 0, 0, 0);
            acc[1][0] = __builtin_amdgcn_mfma_f32_16x16x32_bf16(a1, b0, acc[1][0], 0, 0, 0);
            acc[1][1] = __builtin_amdgcn_mfma_f32_16x16x32_bf16(a1, b1, acc[1][1], 0, 0, 0);
        }
        if (s < 7) {
            int jn = (s + 1) * 512;
            distp += decode16(n0, ri0, fr0, kf0, kqb0, v + jn + cc0, u_r0, negdec, nxt);
            distp += decode16(n1, ri1, fr1, kf1, kqb1, v + jn + cc1, u_r1, negdec, nxt);
        }
        __syncthreads();
    }

    // epilogue: C = srcn + u * acc
    int rq = (l >> 4) * 4;
    #pragma unroll
    for (int ri = 0; ri < 2; ++ri) {
        #pragma unroll
        for (int q = 0; q < 4; ++q) {
            int i = i0 + ri*16 + rq + q;
            float uu = u[i];
            #pragma unroll
            for (int di = 0; di < 2; ++di) {
                int d = 32*w + di*16 + fr;
                size_t idx = (size_t)i*DD + d;
                out[idx] = srcn[idx] + uu * acc[ri][di][q];
            }
        }
    }
    distp = wsum(distp);
    if (l == 0) dsh[w] = distp;
    __syncthreads();
    if (tid == 0) {
        float t = 0.0f;
        #pragma unroll
        for (int ww = 0; ww < 8; ++ww) t += dsh[ww];
        atomicAdd(out + (size_t)NN*DD, t * QINV);
    }
}

// ---------------- host ----------------
extern "C" void kernel_launch(void* const* d_in, const int* in_sizes, int n_in,
                              void* d_out, int out_size, void* d_ws, size_t ws_size,
                              hipStream_t stream) {
    const float* src = (const float*)d_in[0];
    const float* tgt = (const float*)d_in[1];
    float* out = (float*)d_out;
    char* ws = (char*)d_ws;

    constexpr size_t OFF_SRCN = 0;                        // 8192*256*4  = 8388608
    constexpr size_t OFF_SRCB = 8388608;                  // 8192*256*2  = 4194304
    constexpr size_t OFF_TGTB = 12582912;                 // 4096*256*2  = 2097152
    constexpr size_t OFF_TGTT = 14680064;                 // 256*4096*2  = 2097152
    constexpr size_t OFF_WT   = 16777216;                 // 256*4096*2  = 2097152
    constexpr size_t OFF_KQ   = 18874368;                 // 8192*4096*1 = 33554432
    constexpr size_t OFF_PART = 52428800;                 // 256*4096*4  = 4194304
    constexpr size_t OFF_U    = 56623104;                 // 8192*4
    constexpr size_t OFF_V    = 56655872;                 // 4096*4
    constexpr size_t OFF_CMAX = 56672256;                 // 4

    float* srcn = (float*)(ws + OFF_SRCN);
    unsigned short* srcb = (unsigned short*)(ws + OFF_SRCB);
    unsigned short* tgtb = (unsigned short*)(ws + OFF_TGTB);
    unsigned short* tgtT = (unsigned short*)(ws + OFF_TGTT);
    unsigned short* WT   = (unsigned short*)(ws + OFF_WT);
    unsigned char* Kq    = (unsigned char*)(ws + OFF_KQ);
    float* part = (float*)(ws + OFF_PART);
    float* u    = (float*)(ws + OFF_U);
    float* v    = (float*)(ws + OFF_V);
    unsigned int* cmaxu = (unsigned int*)(ws + OFF_CMAX);

    static int attr_done = 0;
    if (!attr_done) {
        (void)hipFuncSetAttribute((const void*)sink_kernel,
                                  hipFuncAttributeMaxDynamicSharedMemorySize,
                                  SINK_SMEM);
        (void)hipFuncSetAttribute((const void*)final_kernel,
                                  hipFuncAttributeMaxDynamicSharedMemorySize,
                                  FIN_SMEM);
        attr_done = 1;
    }

    init_kernel<<<1, 64, 0, stream>>>(cmaxu, out);
    norm_kernel<<<NN + MM, 64, 0, stream>>>(src, tgt, srcn, srcb, tgtb, tgtT);
    dot_kernel<<<(NN/64)*(MM/64), 256, 0, stream>>>(srcb, tgtb, Kq, cmaxu);
    for (int k = 0; k < NIT; ++k) {
        sink_kernel<<<NN/32, 512, SINK_SMEM, stream>>>(Kq, v, u, part, cmaxu, k == 0 ? 1 : 0);
        vred_kernel<<<MM/64, 512, 0, stream>>>(part, v);
    }
    wt_kernel<<<512, 256, 0, stream>>>(tgtT, v, WT);
    final_kernel<<<NN/32, 512, FIN_SMEM, stream>>>(Kq, u, v, WT, srcn, cmaxu, out);
}